// Round 5
// baseline (142.845 us; speedup 1.0000x reference)
//
#include <hip/hip_runtime.h>
#include <hip/hip_bf16.h>
#include <cstdint>
#include <math.h>

#define D_DIM 1024
#define TAU_INV 10.0f
#define BK 64
#define NT (D_DIM / BK)        // 16 K-tiles
#define BM 256

typedef __bf16 bf16x8 __attribute__((ext_vector_type(8)));
typedef float f32x4 __attribute__((ext_vector_type(4)));

#define VMCNT(n) asm volatile("s_waitcnt vmcnt(" #n ")" ::: "memory")
#define BAR() do { asm volatile("" ::: "memory"); \
                   __builtin_amdgcn_s_barrier();  \
                   asm volatile("" ::: "memory"); } while (0)

__device__ __forceinline__ float wave_reduce_add(float v) {
#pragma unroll
    for (int off = 32; off > 0; off >>= 1) v += __shfl_xor(v, off, 64);
    return v;
}

// ---- Kernel A (fused): normalize both rows -> bf16 K, positives, zero rowsum
__global__ __launch_bounds__(256)
void norm_pos_kernel(const float* __restrict__ zi, const float* __restrict__ zj,
                     __hip_bfloat16* __restrict__ K, float* __restrict__ rowsum,
                     float* __restrict__ pos, int n_half) {
    const int i = blockIdx.x;
    const int t = threadIdx.x;                 // 256 threads x 4 floats = 1024
    float4 a = reinterpret_cast<const float4*>(zi + (size_t)i * D_DIM)[t];
    float4 b = reinterpret_cast<const float4*>(zj + (size_t)i * D_DIM)[t];
    float ssa = a.x*a.x + a.y*a.y + a.z*a.z + a.w*a.w;
    float ssb = b.x*b.x + b.y*b.y + b.z*b.z + b.w*b.w;
    float dab = a.x*b.x + a.y*b.y + a.z*b.z + a.w*b.w;
    ssa = wave_reduce_add(ssa);
    ssb = wave_reduce_add(ssb);
    dab = wave_reduce_add(dab);
    __shared__ float wsa[4], wsb[4], wsd[4];
    if ((t & 63) == 0) { wsa[t>>6] = ssa; wsb[t>>6] = ssb; wsd[t>>6] = dab; }
    __syncthreads();
    const float inva = 1.0f / sqrtf(wsa[0] + wsa[1] + wsa[2] + wsa[3]);
    const float invb = 1.0f / sqrtf(wsb[0] + wsb[1] + wsb[2] + wsb[3]);
    union { __hip_bfloat16 h[4]; uint2 u; } pa, pb;
    pa.h[0] = __float2bfloat16(a.x * inva); pa.h[1] = __float2bfloat16(a.y * inva);
    pa.h[2] = __float2bfloat16(a.z * inva); pa.h[3] = __float2bfloat16(a.w * inva);
    pb.h[0] = __float2bfloat16(b.x * invb); pb.h[1] = __float2bfloat16(b.y * invb);
    pb.h[2] = __float2bfloat16(b.z * invb); pb.h[3] = __float2bfloat16(b.w * invb);
    reinterpret_cast<uint2*>(K + (size_t)i * D_DIM)[t] = pa.u;
    reinterpret_cast<uint2*>(K + (size_t)(i + n_half) * D_DIM)[t] = pb.u;
    if (t == 0) {
        pos[i] = (wsd[0] + wsd[1] + wsd[2] + wsd[3]) * inva * invb;
        rowsum[i] = 0.0f;
        rowsum[i + n_half] = 0.0f;
    }
}

// ---- Kernel B: upper-triangular 256x256 tiles, 8-phase schedule ------------
// Tiles (by, bx), by <= bx, 528 blocks. Off-diag: row+col reduction (symmetry);
// diag: row-only, exact diagonal zeroed.
// 8 waves (2M x 4N); per-wave 128x64 output split into 4 quadrants
// (A-half a, B-half b) of 64x32 = acc[a*2+b][4][2]. BK=64, 2-deep LDS dbuf
// (2 x (A 32K + B 32K) = 128 KiB). Per K-tile: 4 phases, one quadrant each:
//   phase q: stage half q of tile t+1 (2 gload_lds) -> vmcnt(6) -> barrier
//            -> ds_read frags (if new) -> [lgkm auto] -> setprio(1) 16 MFMA
//            setprio(0) -> barrier.
// Half issue order {h0=A0, h1=B0, h2=B1, h3=A1}; quadrant order
// (0,0),(0,1),(1,1),(1,0) reads halves {h0+h1, h2, h3, -}. vmcnt(6) at phase q
// leaves outstanding exactly {halves >q of tile t} + {halves <=q of t+1}
// = 6 loads, so the half phase q reads is always resident. Phase 3: no reads.
// Frag reuse: A-frags live 2 phases, B-frag sets live 3 -> 24 ds_read_b128
// per K-tile per wave -> LDS-read (~1540 cyc/CU/K-tile) < MFMA (~2480 cyc).
// LDS swizzle (verified 0-conflict r1/r2): slot_phys = slot_log ^ (row&7),
// inverse-applied on the global staging source (rule #21).
__global__ __launch_bounds__(512, 2)
void simclr_gemm_kernel(const __hip_bfloat16* __restrict__ Kmat,
                        float* __restrict__ rowsum, int n_total) {
    __shared__ char lds[131072];

    const int tid  = threadIdx.x;
    const int lane = tid & 63;
    const int wave = tid >> 6;          // 0..7
    const int wr = wave >> 2;           // 0..1  (64-row panel within quadrant)
    const int wc = wave & 3;            // 0..3  (32-col panel within quadrant)
    const int kgrp = lane >> 4;         // 16B k-slot group

    // bijective XCD swizzle: nwg = 528 = 8 * 66
    const int wg = (blockIdx.x & 7) * 66 + (blockIdx.x >> 3);

    // decode wg -> (by, bx), by <= bx < NB
    const int NB = n_total / BM;        // 32
    int by = 0, start = 0;
    while (wg >= start + (NB - by)) { start += NB - by; ++by; }
    const int bx = by + (wg - start);
    const bool diag = (bx == by);
    const int rowbase = by * BM;
    const int colbase = bx * BM;

    const char* gK = reinterpret_cast<const char*>(Kmat);
    const int srow = tid >> 3;                          // 0..63
    const int sswz = (tid & 7) ^ (srow & 7);            // inverse-swizzled slot

    // stage half h of K-tile tt into buffer tt&1.
    // h: 0 = A rows 0-127, 1 = B rows 0-127, 2 = B rows 128-255, 3 = A rows 128-255
    auto stage_half = [&](int tt, int h) {
        char* buf = lds + (tt & 1) * 65536;
        const size_t kbyte = (size_t)tt * (BK * 2);     // 128 B per row chunk
        const bool isA = (h == 0 || h == 3);
        const int r0 = (h == 0 || h == 1) ? 0 : 128;
        char* dst = buf + (isA ? 0 : 32768) + r0 * 128 + tid * 16;
        const int gbase = isA ? rowbase : colbase;
#pragma unroll
        for (int i = 0; i < 2; ++i) {
            const int row = r0 + i * 64 + srow;
            const char* src = gK + (size_t)(gbase + row) * (D_DIM * 2) + kbyte + sswz * 16;
            __builtin_amdgcn_global_load_lds(
                (const __attribute__((address_space(1))) void*)src,
                (__attribute__((address_space(3))) void*)(dst + i * 8192),
                16, 0, 0);
        }
    };

    f32x4 acc[4][4][2] = {};   // [quad a*2+b][mi][ni]
    bf16x8 af[8], bf0[4], bf1[4];

    auto readA = [&](const char* Ab, int a) {
#pragma unroll
        for (int mi = 0; mi < 4; ++mi) {
            const int row = a * 128 + wr * 64 + mi * 16 + (lane & 15);
#pragma unroll
            for (int kk = 0; kk < 2; ++kk)
                af[mi * 2 + kk] = *reinterpret_cast<const bf16x8*>(
                    lds + (Ab - lds) + row * 128 + (((kk * 4 + kgrp) ^ (lane & 7)) << 4));
        }
    };
    auto readB = [&](const char* Bb, int b, bf16x8* bfr) {
#pragma unroll
        for (int ni = 0; ni < 2; ++ni) {
            const int row = b * 128 + wc * 32 + ni * 16 + (lane & 15);
#pragma unroll
            for (int kk = 0; kk < 2; ++kk)
                bfr[ni * 2 + kk] = *reinterpret_cast<const bf16x8*>(
                    lds + (Bb - lds) + row * 128 + (((kk * 4 + kgrp) ^ (lane & 7)) << 4));
        }
    };
    auto mmaq = [&](int qi, const bf16x8* bfr) {
        __builtin_amdgcn_s_setprio(1);
#pragma unroll
        for (int mi = 0; mi < 4; ++mi)
#pragma unroll
            for (int ni = 0; ni < 2; ++ni)
#pragma unroll
                for (int kk = 0; kk < 2; ++kk)
                    acc[qi][mi][ni] = __builtin_amdgcn_mfma_f32_16x16x32_bf16(
                        af[mi * 2 + kk], bfr[ni * 2 + kk], acc[qi][mi][ni], 0, 0, 0);
        __builtin_amdgcn_s_setprio(0);
    };

    // prologue: stage all 4 halves of K-tile 0
    stage_half(0, 0); stage_half(0, 1); stage_half(0, 2); stage_half(0, 3);

    for (int t = 0; t < NT - 1; ++t) {
        const char* Ab = lds + (t & 1) * 65536;
        const char* Bb = Ab + 32768;
        // phase 0: quad (0,0) — needs A0(h0), B0(h1)
        stage_half(t + 1, 0);
        VMCNT(6); BAR();
        readA(Ab, 0); readB(Bb, 0, bf0);
        mmaq(0, bf0);
        BAR();
        // phase 1: quad (0,1) — needs B1(h2)
        stage_half(t + 1, 1);
        VMCNT(6); BAR();
        readB(Bb, 1, bf1);
        mmaq(1, bf1);
        BAR();
        // phase 2: quad (1,1) — needs A1(h3)
        stage_half(t + 1, 2);
        VMCNT(6); BAR();
        readA(Ab, 1);
        mmaq(3, bf1);
        BAR();
        // phase 3: quad (1,0) — all operands in regs
        stage_half(t + 1, 3);
        mmaq(2, bf0);
        BAR();
    }
    {   // last K-tile (NT-1): no staging; drain by halves
        const char* Ab = lds + ((NT - 1) & 1) * 65536;
        const char* Bb = Ab + 32768;
        VMCNT(4); BAR();
        readA(Ab, 0); readB(Bb, 0, bf0);
        mmaq(0, bf0);
        BAR();
        VMCNT(2); BAR();
        readB(Bb, 1, bf1);
        mmaq(1, bf1);
        BAR();
        VMCNT(0); BAR();
        readA(Ab, 1);
        mmaq(3, bf1);
        BAR();
        mmaq(2, bf0);
    }

    // Epilogue. C-frag: col = lane&15, row = (lane>>4)*4 + reg.
    // quad (a,b): grow = rowbase + a*128 + wr*64 + mi*16 + (lane>>4)*4 + reg
    //             gcol = colbase + b*128 + wc*32 + ni*16 + (lane&15)
    float colpart[4] = {0.0f, 0.0f, 0.0f, 0.0f};
#pragma unroll
    for (int a = 0; a < 2; ++a) {
#pragma unroll
        for (int mi = 0; mi < 4; ++mi) {
#pragma unroll
            for (int reg = 0; reg < 4; ++reg) {
                const int grow = rowbase + a * 128 + wr * 64 + mi * 16 +
                                 ((lane >> 4) << 2) + reg;
                float rowpart = 0.0f;
#pragma unroll
                for (int b = 0; b < 2; ++b) {
#pragma unroll
                    for (int ni = 0; ni < 2; ++ni) {
                        const int gcol = colbase + b * 128 + wc * 32 + ni * 16 + (lane & 15);
                        float e = __expf(acc[a * 2 + b][mi][ni][reg] * TAU_INV);
                        if (diag && grow == gcol) e = 0.0f;
                        rowpart += e;
                        colpart[b * 2 + ni] += e;
                    }
                }
#pragma unroll
                for (int off = 1; off < 16; off <<= 1)
                    rowpart += __shfl_xor(rowpart, off, 64);
                if ((lane & 15) == 0) atomicAdd(&rowsum[grow], rowpart);
            }
        }
    }
    if (!diag) {
#pragma unroll
        for (int b = 0; b < 2; ++b) {
#pragma unroll
            for (int ni = 0; ni < 2; ++ni) {
                float cp = colpart[b * 2 + ni];
                cp += __shfl_xor(cp, 16, 64);
                cp += __shfl_xor(cp, 32, 64);
                if (lane < 16)
                    atomicAdd(&rowsum[colbase + b * 128 + wc * 32 + ni * 16 + lane], cp);
            }
        }
    }
}

// ---- Kernel C: loss = mean(log(denom) - pos/tau) ---------------------------
__global__ __launch_bounds__(256)
void loss_kernel(const float* __restrict__ rowsum, const float* __restrict__ pos,
                 float* __restrict__ out, int n_total, int n_half) {
    const int t = threadIdx.x;
    float acc = 0.0f;
    for (int r = t; r < n_total; r += 256) {
        const int pi = (r < n_half) ? r : (r - n_half);
        acc += logf(rowsum[r]) - TAU_INV * pos[pi];
    }
    acc = wave_reduce_add(acc);
    __shared__ float ws4[4];
    if ((t & 63) == 0) ws4[t >> 6] = acc;
    __syncthreads();
    if (t == 0) out[0] = (ws4[0] + ws4[1] + ws4[2] + ws4[3]) / (float)n_total;
}

extern "C" void kernel_launch(void* const* d_in, const int* in_sizes, int n_in,
                              void* d_out, int out_size, void* d_ws, size_t ws_size,
                              hipStream_t stream) {
    const float* zi = (const float*)d_in[0];
    const float* zj = (const float*)d_in[1];
    float* out = (float*)d_out;

    const int n_half  = in_sizes[0] / D_DIM;   // 4096
    const int n_total = 2 * n_half;            // 8192

    char* ws = (char*)d_ws;
    __hip_bfloat16* K = (__hip_bfloat16*)ws;
    size_t off = (size_t)n_total * D_DIM * sizeof(__hip_bfloat16);
    float* rowsum = (float*)(ws + off); off += (size_t)n_total * 4;
    float* pos    = (float*)(ws + off); off += (size_t)n_half * 4;

    norm_pos_kernel<<<n_half, 256, 0, stream>>>(zi, zj, K, rowsum, pos, n_half);

    // upper-triangular 256x256 tiles: 32*33/2 = 528 blocks
    simclr_gemm_kernel<<<528, 512, 0, stream>>>(K, rowsum, n_total);

    loss_kernel<<<1, 256, 0, stream>>>(rowsum, pos, out, n_total, n_half);
}